// Round 12
// baseline (5957.542 us; speedup 1.0000x reference)
//
#include <hip/hip_runtime.h>

// Problem constants (from reference)
#define B_TREES 32
#define DEPTH   12
#define M_NODES 4095                  // 2^12 - 1
#define N_NODES (B_TREES * M_NODES)   // 131040
#define HDIM    256
#define VOCAB   32000
#define NCLS    20
#define LEAFROWS 65536                // 32 * 2048 leaves
#define LDSH_S  20                    // padded stride of leaf h transpose tile
#define NBLK    1024                  // 4 blocks/CU x 256 CUs (co-resident)
#define NTHR    256
#define LEAF_TPW 16

typedef _Float16 f16;
typedef _Float16 f16x8 __attribute__((ext_vector_type(8)));
typedef _Float16 f16x4 __attribute__((ext_vector_type(4)));
typedef _Float16 f16x2 __attribute__((ext_vector_type(2)));
typedef float    f32x4 __attribute__((ext_vector_type(4)));

__device__ __forceinline__ float sigf(float x)      { return 1.0f / (1.0f + __expf(-x)); }
__device__ __forceinline__ float tanh_fast(float x) { return 1.0f - 2.0f / (1.0f + __expf(2.0f * x)); }

// Manual grid barrier: monotonic counter, all NBLK blocks co-resident.
// Release fence before arrive, acquire fence after release from spin.
__device__ __forceinline__ void gbar(unsigned* bar, unsigned want)
{
    __threadfence();                   // publish this thread's global writes
    __syncthreads();                   // whole block arrived (drains vmcnt)
    if (threadIdx.x == 0) {
        __hip_atomic_fetch_add(bar, 1u, __ATOMIC_RELEASE, __HIP_MEMORY_SCOPE_AGENT);
        unsigned spins = 0;
        while (__hip_atomic_load(bar, __ATOMIC_ACQUIRE, __HIP_MEMORY_SCOPE_AGENT) < want) {
            __builtin_amdgcn_s_sleep(2);
            if (++spins > 100000000u) break;   // fail-fast instead of hang
        }
    }
    __syncthreads();
    __threadfence();                   // invalidate stale cached lines
}

__global__ void zero_kernel(unsigned* bar) { if (threadIdx.x == 0) *bar = 0u; }

// ---------------------------------------------------------------------------
// Mega kernel: convert -> leaf -> 11 fused levels -> out, one launch.
// Block bx: col-group cg = bx & 15 (16 output cols), row-group rg = bx >> 4.
// ---------------------------------------------------------------------------
__global__ __launch_bounds__(256, 4) void mega_kernel(
    const int* __restrict__ x,
    const float4* __restrict__ Emb,  const float4* __restrict__ Wiou,
    const float4* __restrict__ Uiou, const float4* __restrict__ Uf,
    const float4* __restrict__ Wout,
    const float* __restrict__ b_iou, const float* __restrict__ b_f,
    const float* __restrict__ bout,
    f16* __restrict__ Emb16, f16* __restrict__ Wiou16,
    f16* __restrict__ Uiou16, f16* __restrict__ Uf16,
    f16* __restrict__ Wout16,
    f16* __restrict__ h16, f16* __restrict__ cA, f16* __restrict__ cB,
    float* __restrict__ out, unsigned* __restrict__ bar)
{
    __shared__ f16 wlds[2048 * 8];        // 32 KB weight fragments
    __shared__ f16 scratch[4][512];       // 4 KB per-wave h transpose tiles

    const int tid  = threadIdx.x;
    const int bx   = blockIdx.x;
    const int lane = tid & 63;
    const int w    = tid >> 6;
    const int quad = lane >> 4;
    const int l15  = lane & 15;
    const int qk   = quad * 8;
    const int cg   = bx & 15, rg = bx >> 4;
    const int cb0  = cg * 16;
    unsigned bgen = 0;

    // ---------------- Phase C: fp32 -> fp16 conversion ----------------
    {
        const int gt = bx * NTHR + tid;                  // 0..262143
        for (int i = gt; i < VOCAB * HDIM / 4; i += NBLK * NTHR) {
            float4 v = Emb[i];
            f16x4 r; r[0]=(f16)v.x; r[1]=(f16)v.y; r[2]=(f16)v.z; r[3]=(f16)v.w;
            ((f16x4*)Emb16)[i] = r;
        }
        if (gt < 768 * HDIM / 4) {
            float4 v = Wiou[gt];
            f16x4 r; r[0]=(f16)v.x; r[1]=(f16)v.y; r[2]=(f16)v.z; r[3]=(f16)v.w;
            ((f16x4*)Wiou16)[gt] = r;
            float4 u = Uiou[gt];
            f16x4 s; s[0]=(f16)u.x; s[1]=(f16)u.y; s[2]=(f16)u.z; s[3]=(f16)u.w;
            ((f16x4*)Uiou16)[gt] = s;
        }
        if (gt < HDIM * HDIM / 4) {
            float4 v = Uf[gt];
            f16x4 r; r[0]=(f16)v.x; r[1]=(f16)v.y; r[2]=(f16)v.z; r[3]=(f16)v.w;
            ((f16x4*)Uf16)[gt] = r;
        }
        if (gt < 32 * HDIM / 4) {
            int row = gt >> 6;
            f16x4 r = {};
            if (row < NCLS) {
                float4 v = Wout[gt];
                r[0]=(f16)v.x; r[1]=(f16)v.y; r[2]=(f16)v.z; r[3]=(f16)v.w;
            }
            ((f16x4*)Wout16)[gt] = r;
        }
    }
    bgen += NBLK; gbar(bar, bgen);

    // ---------------- Phase L: leaf GEMM (round-10 datapath) ----------------
    {
        // Stage Wiou 16-col tile (frag f = mat*512 + ks*64 + quad*16 + col)
        #pragma unroll
        for (int i = 0; i < 6; ++i) {
            int f = i * 256 + tid;
            int mat = f >> 9, r = f & 511, ks = r >> 6, q = (r >> 4) & 3, c = r & 15;
            *(f16x8*)(wlds + f * 8) = *(const f16x8*)(Wiou16 +
                (mat * 256 + cb0 + c) * HDIM + ks * 32 + q * 8);
        }
        __syncthreads();

        const float bi = b_iou[cb0 + l15];
        const float bo = b_iou[256 + cb0 + l15];
        const float bu = b_iou[512 + cb0 + l15];

        const int row0 = (rg * 4 + w) * (LEAF_TPW * 16);   // wave's 256 rows

        int nodeRow = (row0 >> 11) * M_NODES + 2047 + (row0 & 2047);
        int embBase = x[nodeRow + l15] * HDIM;
        f16x8 a[8];
        #pragma unroll
        for (int ks = 0; ks < 8; ++ks)
            a[ks] = *(const f16x8*)(Emb16 + embBase + ks * 32 + qk);

        for (int rt = 0; rt < LEAF_TPW; ++rt) {
            const int rw = row0 + rt * 16;
            const int curNode = nodeRow;
            f16x8 ac[8];
            #pragma unroll
            for (int ks = 0; ks < 8; ++ks) ac[ks] = a[ks];

            if (rt + 1 < LEAF_TPW) {
                const int rwn = rw + 16;
                nodeRow = (rwn >> 11) * M_NODES + 2047 + (rwn & 2047);
                embBase = x[nodeRow + l15] * HDIM;
                #pragma unroll
                for (int ks = 0; ks < 8; ++ks)
                    a[ks] = *(const f16x8*)(Emb16 + embBase + ks * 32 + qk);
            }

            f32x4 acc[3] = {};
            #pragma unroll
            for (int ks = 0; ks < 8; ++ks)
                #pragma unroll
                for (int mat = 0; mat < 3; ++mat) {
                    f16x8 wf = *(const f16x8*)(wlds +
                        ((mat * 8 + ks) * 64 + quad * 16 + l15) * 8);
                    acc[mat] = __builtin_amdgcn_mfma_f32_16x16x32_f16(
                        ac[ks], wf, acc[mat], 0, 0, 0);
                }

            f16x4 cv;
            #pragma unroll
            for (int r = 0; r < 4; ++r) {
                float i_ = acc[0][r] + bi;
                float o_ = acc[1][r] + bo;
                float u_ = acc[2][r] + bu;
                float c  = sigf(i_) * tanh_fast(u_);
                float h  = sigf(o_) * tanh_fast(c);
                cv[r] = (f16)c;
                scratch[w][(quad * 4 + r) * LDSH_S + l15] = (f16)h;
            }
            *(f16x4*)(cA + (cb0 + l15) * LEAFROWS + rw + quad * 4) = cv;

            {
                int row_l = lane >> 2, cpos = (lane & 3) * 4;
                f16x4 v = *(const f16x4*)(&scratch[w][row_l * LDSH_S + cpos]);
                *(f16x4*)(h16 + (curNode + row_l) * HDIM + cb0 + cpos) = v;
            }
        }
    }
    bgen += NBLK; gbar(bar, bgen);

    // ---------------- Stage Uf + Uiou once for all levels ----------------
    #pragma unroll
    for (int i = 0; i < 8; ++i) {
        int f = i * 256 + tid;
        int mat = f >> 9, r = f & 511, ks = r >> 6, q = (r >> 4) & 3, c = r & 15;
        const f16* src = (mat == 0)
            ? (Uf16 + (cb0 + c) * HDIM + ks * 32 + q * 8)
            : (Uiou16 + ((mat - 1) * 256 + cb0 + c) * HDIM + ks * 32 + q * 8);
        *(f16x8*)(wlds + f * 8) = *(const f16x8*)src;
    }
    __syncthreads();

    // ---------------- Phase V: levels 10..0 (round-11 v3 datapath) ---------
    {
        const float bi  = b_iou[cb0 + l15];
        const float bo  = b_iou[256 + cb0 + l15];
        const float bu  = b_iou[512 + cb0 + l15];
        const float bfv = b_f[cb0 + l15];
        const int vw = rg * 4 + w;                        // 0..255 per col-group

        f16* cin  = cA;
        f16* cout_ = cB;
        for (int l = 10; l >= 0; --l) {
            const int rows_p = B_TREES << l;
            const int rows_c = rows_p * 2;
            const int lc = l + 1;
            const int maskc = (1 << lc) - 1;
            const int maskp = (1 << l) - 1;
            const int tiles = rows_p >> 5;                // 32-parent tiles
            const int tpl   = (tiles + 255) >> 8;
            int t0 = vw * tpl;
            int t1 = t0 + tpl; if (t1 > tiles) t1 = tiles;

            for (int t = t0; t < t1; ++t) {
                const int pw = t * 32;
                const int cw = 2 * pw;

                int childBase[4];
                #pragma unroll
                for (int s = 0; s < 4; ++s) {
                    int cl = cw + s * 16 + l15;
                    childBase[s] = ((cl >> lc) * M_NODES + maskc + (cl & maskc)) * HDIM;
                }
                f16x4 cc[4];
                #pragma unroll
                for (int s = 0; s < 4; ++s)
                    cc[s] = *(const f16x4*)(cin +
                        (cb0 + l15) * rows_c + cw + s * 16 + quad * 4);

                f32x4 accf[4] = {};
                f32x4 au[3][4] = {};
                #pragma unroll
                for (int ks = 0; ks < 8; ++ks) {
                    const int k0 = ks * 32 + qk;
                    f16x8 a[4];
                    #pragma unroll
                    for (int s = 0; s < 4; ++s)
                        a[s] = *(const f16x8*)(h16 + childBase[s] + k0);
                    f16x8 wfF = *(const f16x8*)(wlds + (ks * 64 + quad * 16 + l15) * 8);
                    #pragma unroll
                    for (int s = 0; s < 4; ++s)
                        accf[s] = __builtin_amdgcn_mfma_f32_16x16x32_f16(
                            a[s], wfF, accf[s], 0, 0, 0);
                    #pragma unroll
                    for (int m = 0; m < 3; ++m) {
                        f16x8 wm = *(const f16x8*)(wlds +
                            (((m + 1) * 8 + ks) * 64 + quad * 16 + l15) * 8);
                        #pragma unroll
                        for (int s = 0; s < 4; ++s)
                            au[m][s] = __builtin_amdgcn_mfma_f32_16x16x32_f16(
                                a[s], wm, au[m][s], 0, 0, 0);
                    }
                }

                #pragma unroll
                for (int s = 0; s < 4; ++s) {
                    f16x2 cpack;
                    #pragma unroll
                    for (int pr = 0; pr < 2; ++pr) {
                        float f0 = sigf(accf[s][2 * pr]     + bfv);
                        float f1 = sigf(accf[s][2 * pr + 1] + bfv);
                        float fc = f0 * (float)cc[s][2 * pr]
                                 + f1 * (float)cc[s][2 * pr + 1];
                        float i_ = au[0][s][2 * pr] + au[0][s][2 * pr + 1] + bi;
                        float o_ = au[1][s][2 * pr] + au[1][s][2 * pr + 1] + bo;
                        float u_ = au[2][s][2 * pr] + au[2][s][2 * pr + 1] + bu;
                        float c  = sigf(i_) * tanh_fast(u_) + fc;
                        float h  = sigf(o_) * tanh_fast(c);
                        cpack[pr] = (f16)c;
                        scratch[w][(s * 8 + quad * 2 + pr) * 16 + l15] = (f16)h;
                    }
                    *(f16x2*)(cout_ + (cb0 + l15) * rows_p + pw + s * 8 + quad * 2) = cpack;
                }

                {
                    int prow = lane >> 1, cpos = (lane & 1) * 8;
                    int p = pw + prow;
                    int b = p >> l, tt = p & maskp;
                    int node = b * M_NODES + (1 << l) - 1 + tt;
                    f16x8 v = *(const f16x8*)(&scratch[w][prow * 16 + cpos]);
                    *(f16x8*)(h16 + node * HDIM + cb0 + cpos) = v;
                }
            }

            bgen += NBLK; gbar(bar, bgen);
            f16* tmp = cin; cin = cout_; cout_ = tmp;
        }
    }

    // ---------------- Phase O: output GEMM ----------------
    {
        f16x8 wfk[2][8];
        #pragma unroll
        for (int cf = 0; cf < 2; ++cf)
            #pragma unroll
            for (int ks = 0; ks < 8; ++ks)
                wfk[cf][ks] = *(const f16x8*)(Wout16 +
                    (cf * 16 + l15) * HDIM + ks * 32 + qk);
        float bo2[2];
        #pragma unroll
        for (int cf = 0; cf < 2; ++cf) {
            int col = cf * 16 + l15;
            bo2[cf] = bout[col < NCLS ? col : 0];
        }

        const int ntot = N_NODES / 16;                 // 8190
        const int gw   = bx * 4 + w;                   // 0..4095
        int t0 = gw * 2;
        int tn = ntot - t0; if (tn > 2) tn = 2; if (tn < 0) tn = 0;

        for (int i = 0; i < tn; ++i) {
            const int rw = (t0 + i) * 16;
            f32x4 acc[2] = {};
            #pragma unroll
            for (int ks = 0; ks < 8; ++ks) {
                f16x8 a = *(const f16x8*)(h16 + (rw + l15) * HDIM + ks * 32 + qk);
                #pragma unroll
                for (int cf = 0; cf < 2; ++cf)
                    acc[cf] = __builtin_amdgcn_mfma_f32_16x16x32_f16(
                        a, wfk[cf][ks], acc[cf], 0, 0, 0);
            }
            #pragma unroll
            for (int cf = 0; cf < 2; ++cf) {
                const int col = cf * 16 + l15;
                if (col < NCLS) {
                    #pragma unroll
                    for (int r = 0; r < 4; ++r)
                        out[(rw + quad * 4 + r) * NCLS + col] = acc[cf][r] + bo2[cf];
                }
            }
        }
    }
}

// ---------------------------------------------------------------------------
extern "C" void kernel_launch(void* const* d_in, const int* in_sizes, int n_in,
                              void* d_out, int out_size, void* d_ws, size_t ws_size,
                              hipStream_t stream)
{
    const int*   x     = (const int*)d_in[0];
    // d_in[1] = x_mask: leaf structure is static — folded into indexing.
    const float* Emb   = (const float*)d_in[2];
    const float* W_iou = (const float*)d_in[3];
    const float* b_iou = (const float*)d_in[4];
    const float* U_iou = (const float*)d_in[5];
    const float* U_f   = (const float*)d_in[6];
    const float* b_f   = (const float*)d_in[7];
    const float* W_out = (const float*)d_in[8];
    const float* b_out = (const float*)d_in[9];
    float* out = (float*)d_out;

    char* ws = (char*)d_ws;
    size_t off = 0;
    auto take = [&](size_t bytes) -> char* {
        char* p = ws + off; off += (bytes + 255) & ~(size_t)255; return p;
    };
    f16* h16    = (f16*)take((size_t)N_NODES * HDIM * 2);
    f16* cA     = (f16*)take((size_t)HDIM * LEAFROWS * 2);        // [256][65536]
    f16* cB     = (f16*)take((size_t)HDIM * (LEAFROWS / 2) * 2);  // [256][32768]
    f16* Emb16  = (f16*)take((size_t)VOCAB * HDIM * 2);
    f16* Wiou16 = (f16*)take((size_t)768 * HDIM * 2);
    f16* Uiou16 = (f16*)take((size_t)768 * HDIM * 2);
    f16* Uf16   = (f16*)take((size_t)HDIM * HDIM * 2);
    f16* Wout16 = (f16*)take((size_t)32 * HDIM * 2);
    unsigned* bar = (unsigned*)take(256);

    zero_kernel<<<1, 64, 0, stream>>>(bar);

    void* args[] = {
        (void*)&x, (void*)&Emb, (void*)&W_iou, (void*)&U_iou, (void*)&U_f,
        (void*)&W_out, (void*)&b_iou, (void*)&b_f, (void*)&b_out,
        (void*)&Emb16, (void*)&Wiou16, (void*)&Uiou16, (void*)&Uf16,
        (void*)&Wout16, (void*)&h16, (void*)&cA, (void*)&cB,
        (void*)&out, (void*)&bar
    };
    (void)args;
    mega_kernel<<<NBLK, NTHR, 0, stream>>>(
        x, (const float4*)Emb, (const float4*)W_iou, (const float4*)U_iou,
        (const float4*)U_f, (const float4*)W_out, b_iou, b_f, b_out,
        Emb16, Wiou16, Uiou16, Uf16, Wout16, h16, cA, cB, out, bar);
}